// Round 1
// baseline (1025.713 us; speedup 1.0000x reference)
//
#include <hip/hip_runtime.h>
#include <hip/hip_bf16.h>

#define N_TOK 8192
#define DIM   1024
#define HID   4096
#define NEXP  8
#define TOPK  2
#define M_TOT (N_TOK*TOPK)

typedef __bf16 bf16x8 __attribute__((ext_vector_type(8)));
typedef float  f32x4  __attribute__((ext_vector_type(4)));

__device__ __forceinline__ unsigned short f2bf(float f) {
    union { __hip_bfloat16 h; unsigned short u; } c;
    c.h = __float2bfloat16(f);
    return c.u;
}

// ---------------- fp32 -> bf16 conversion (vectorized) ----------------
__global__ void cvt_kernel(const float* __restrict__ in, unsigned short* __restrict__ out, int n4) {
    int i = blockIdx.x * blockDim.x + threadIdx.x;
    int stride = gridDim.x * blockDim.x;
    for (; i < n4; i += stride) {
        float4 v = reinterpret_cast<const float4*>(in)[i];
        ushort4 o;
        o.x = f2bf(v.x); o.y = f2bf(v.y); o.z = f2bf(v.z); o.w = f2bf(v.w);
        reinterpret_cast<ushort4*>(out)[i] = o;
    }
}

// ---------------- router: logits, softmax, top-2, counts ----------------
__global__ __launch_bounds__(64) void router_kernel(
    const float* __restrict__ x, const float* __restrict__ rw, const float* __restrict__ rb,
    int* __restrict__ tidx, float* __restrict__ tgate, int* __restrict__ counts)
{
    int t = blockIdx.x;
    int lane = threadIdx.x;
    const float* xr = x + (size_t)t * DIM;
    float acc[NEXP];
#pragma unroll
    for (int e = 0; e < NEXP; ++e) acc[e] = 0.f;
    for (int i = lane; i < DIM; i += 64) {
        float xv = xr[i];
#pragma unroll
        for (int e = 0; e < NEXP; ++e) acc[e] += xv * rw[e*DIM + i];
    }
#pragma unroll
    for (int e = 0; e < NEXP; ++e) {
        float v = acc[e];
#pragma unroll
        for (int off = 32; off >= 1; off >>= 1) v += __shfl_xor(v, off);
        acc[e] = v + rb[e];
    }
    // top-2 on logits (softmax is monotonic); strict > keeps lowest index on ties (jax semantics)
    int i0 = 0;
#pragma unroll
    for (int e = 1; e < NEXP; ++e) if (acc[e] > acc[i0]) i0 = e;
    int i1 = (i0 == 0) ? 1 : 0;
#pragma unroll
    for (int e = 0; e < NEXP; ++e) if (e != i0 && acc[e] > acc[i1]) i1 = e;

    float mx = acc[i0];
    float den = 0.f;
    float pe[NEXP];
#pragma unroll
    for (int e = 0; e < NEXP; ++e) { pe[e] = __expf(acc[e] - mx); den += pe[e]; }
    float inv = 1.f / den;
    if (lane == 0) {
        tidx[2*t]   = i0;  tidx[2*t+1]  = i1;
        tgate[2*t]  = pe[i0]*inv; tgate[2*t+1] = pe[i1]*inv;
        atomicAdd(&counts[i0], 1);
        atomicAdd(&counts[i1], 1);
    }
}

__global__ void prefix_kernel(const int* __restrict__ counts, int* __restrict__ offsets) {
    if (threadIdx.x == 0 && blockIdx.x == 0) {
        int s = 0;
        for (int e = 0; e < NEXP; ++e) { offsets[e] = s; s += counts[e]; }
    }
}

__global__ void assign_kernel(const int* __restrict__ tidx, const float* __restrict__ tgate,
                              const int* __restrict__ offsets, int* __restrict__ counts2,
                              int* __restrict__ rowtok, float* __restrict__ rowgate)
{
    int t = blockIdx.x * blockDim.x + threadIdx.x;
    if (t >= N_TOK) return;
#pragma unroll
    for (int k = 0; k < TOPK; ++k) {
        int e = tidx[2*t+k];
        int pos = atomicAdd(&counts2[e], 1);
        int r = offsets[e] + pos;
        rowtok[r]  = t;
        rowgate[r] = tgate[2*t+k];
    }
}

// ---------------- GEMM1: h = gelu(Xg @ w1[e]^T + b1[e]), store bf16 ----------------
// tile 128x128, BK=32, 4 waves each computing 64x64 (4x4 frags of 16x16x32 MFMA)
__global__ __launch_bounds__(256) void gemm1_kernel(
    const unsigned short* __restrict__ xb,      // N x D bf16
    const unsigned short* __restrict__ w1b,     // E x H x D bf16
    const float* __restrict__ b1,               // E x H
    const int* __restrict__ rowtok,
    const int* __restrict__ counts, const int* __restrict__ offsets,
    unsigned short* __restrict__ hg)            // M_TOT x H bf16 (compact)
{
    int e   = blockIdx.z;
    int cnt = counts[e];
    int mt  = blockIdx.y;
    if (mt * 128 >= cnt) return;
    int base  = offsets[e];
    int nbase = blockIdx.x * 128;

    __shared__ unsigned short As[128*32];
    __shared__ unsigned short Bs[128*32];
    __shared__ int rowids[128];

    int tid = threadIdx.x;
    if (tid < 128) {
        int r = mt*128 + tid;
        rowids[tid] = rowtok[base + (r < cnt ? r : cnt - 1)];
    }
    __syncthreads();

    int srow = tid >> 2;          // 0..63
    int scol = (tid & 3) << 3;    // 0,8,16,24
    const unsigned short* wE  = w1b + (size_t)e * HID * DIM;
    const unsigned short* aP0 = xb + (size_t)rowids[srow]      * DIM + scol;
    const unsigned short* aP1 = xb + (size_t)rowids[srow + 64] * DIM + scol;
    const unsigned short* bP0 = wE + (size_t)(nbase + srow) * DIM + scol;
    const unsigned short* bP1 = bP0 + (size_t)64 * DIM;

    unsigned short* as0 = &As[srow       *32 + scol];
    unsigned short* as1 = &As[(srow + 64)*32 + scol];
    unsigned short* bs0 = &Bs[srow       *32 + scol];
    unsigned short* bs1 = &Bs[(srow + 64)*32 + scol];

    int lane = tid & 63;
    int wid  = tid >> 6;
    int wr = (wid >> 1) << 6;
    int wc = (wid & 1)  << 6;
    int fr = lane & 15;
    int fk = (lane >> 4) << 3;

    f32x4 acc[4][4];
#pragma unroll
    for (int m = 0; m < 4; ++m)
#pragma unroll
        for (int n = 0; n < 4; ++n)
#pragma unroll
            for (int j = 0; j < 4; ++j) acc[m][n][j] = 0.f;

    for (int k0 = 0; k0 < DIM; k0 += 32) {
        *(uint4*)as0 = *(const uint4*)(aP0 + k0);
        *(uint4*)as1 = *(const uint4*)(aP1 + k0);
        *(uint4*)bs0 = *(const uint4*)(bP0 + k0);
        *(uint4*)bs1 = *(const uint4*)(bP1 + k0);
        __syncthreads();

        bf16x8 af[4], bfr[4];
#pragma unroll
        for (int m = 0; m < 4; ++m) af[m]  = *(const bf16x8*)&As[(wr + m*16 + fr)*32 + fk];
#pragma unroll
        for (int n = 0; n < 4; ++n) bfr[n] = *(const bf16x8*)&Bs[(wc + n*16 + fr)*32 + fk];
#pragma unroll
        for (int m = 0; m < 4; ++m)
#pragma unroll
            for (int n = 0; n < 4; ++n)
                acc[m][n] = __builtin_amdgcn_mfma_f32_16x16x32_bf16(af[m], bfr[n], acc[m][n], 0, 0, 0);
        __syncthreads();
    }

    const float* b1e = b1 + (size_t)e * HID;
#pragma unroll
    for (int m = 0; m < 4; ++m) {
        int rbase = wr + m*16 + ((lane >> 4) << 2);
#pragma unroll
        for (int j = 0; j < 4; ++j) {
            int grow = mt*128 + rbase + j;
            if (grow < cnt) {
                size_t rowoff = (size_t)(base + grow) * HID;
#pragma unroll
                for (int n = 0; n < 4; ++n) {
                    int col = nbase + wc + n*16 + fr;
                    float v = acc[m][n][j] + b1e[col];
                    // gelu (tanh approximation, jax default)
                    float u  = 0.7978845608028654f * (v + 0.044715f * v * v * v);
                    float ex = __expf(2.f * u);
                    float th = 1.f - 2.f / (ex + 1.f);
                    float g  = 0.5f * v * (1.f + th);
                    hg[rowoff + col] = f2bf(g);
                }
            }
        }
    }
}

// ---------------- GEMM2: y[tok] += gate * (hg @ w2[e]^T + b2[e]) ----------------
__global__ __launch_bounds__(256) void gemm2_kernel(
    const unsigned short* __restrict__ hg,      // M_TOT x H bf16
    const unsigned short* __restrict__ w2b,     // E x D x H bf16
    const float* __restrict__ b2,               // E x D
    const int* __restrict__ rowtok, const float* __restrict__ rowgate,
    const int* __restrict__ counts, const int* __restrict__ offsets,
    float* __restrict__ y)                      // N x D fp32 (pre-zeroed)
{
    int e   = blockIdx.z;
    int cnt = counts[e];
    int mt  = blockIdx.y;
    if (mt * 128 >= cnt) return;
    int base  = offsets[e];
    int nbase = blockIdx.x * 128;

    __shared__ unsigned short As[128*32];
    __shared__ unsigned short Bs[128*32];

    int tid  = threadIdx.x;
    int srow = tid >> 2;
    int scol = (tid & 3) << 3;
    int ar0 = mt*128 + srow;      if (ar0 >= cnt) ar0 = cnt - 1;
    int ar1 = mt*128 + srow + 64; if (ar1 >= cnt) ar1 = cnt - 1;
    const unsigned short* aP0 = hg + (size_t)(base + ar0) * HID + scol;
    const unsigned short* aP1 = hg + (size_t)(base + ar1) * HID + scol;
    const unsigned short* wE  = w2b + (size_t)e * DIM * HID;
    const unsigned short* bP0 = wE + (size_t)(nbase + srow) * HID + scol;
    const unsigned short* bP1 = bP0 + (size_t)64 * HID;

    unsigned short* as0 = &As[srow       *32 + scol];
    unsigned short* as1 = &As[(srow + 64)*32 + scol];
    unsigned short* bs0 = &Bs[srow       *32 + scol];
    unsigned short* bs1 = &Bs[(srow + 64)*32 + scol];

    int lane = tid & 63;
    int wid  = tid >> 6;
    int wr = (wid >> 1) << 6;
    int wc = (wid & 1)  << 6;
    int fr = lane & 15;
    int fk = (lane >> 4) << 3;

    f32x4 acc[4][4];
#pragma unroll
    for (int m = 0; m < 4; ++m)
#pragma unroll
        for (int n = 0; n < 4; ++n)
#pragma unroll
            for (int j = 0; j < 4; ++j) acc[m][n][j] = 0.f;

    for (int k0 = 0; k0 < HID; k0 += 32) {
        *(uint4*)as0 = *(const uint4*)(aP0 + k0);
        *(uint4*)as1 = *(const uint4*)(aP1 + k0);
        *(uint4*)bs0 = *(const uint4*)(bP0 + k0);
        *(uint4*)bs1 = *(const uint4*)(bP1 + k0);
        __syncthreads();

        bf16x8 af[4], bfr[4];
#pragma unroll
        for (int m = 0; m < 4; ++m) af[m]  = *(const bf16x8*)&As[(wr + m*16 + fr)*32 + fk];
#pragma unroll
        for (int n = 0; n < 4; ++n) bfr[n] = *(const bf16x8*)&Bs[(wc + n*16 + fr)*32 + fk];
#pragma unroll
        for (int m = 0; m < 4; ++m)
#pragma unroll
            for (int n = 0; n < 4; ++n)
                acc[m][n] = __builtin_amdgcn_mfma_f32_16x16x32_bf16(af[m], bfr[n], acc[m][n], 0, 0, 0);
        __syncthreads();
    }

    const float* b2e = b2 + (size_t)e * DIM;
#pragma unroll
    for (int m = 0; m < 4; ++m) {
        int rbase = wr + m*16 + ((lane >> 4) << 2);
#pragma unroll
        for (int j = 0; j < 4; ++j) {
            int grow = mt*128 + rbase + j;
            if (grow < cnt) {
                int tok = rowtok[base + grow];
                float g = rowgate[base + grow];
#pragma unroll
                for (int n = 0; n < 4; ++n) {
                    int col = nbase + wc + n*16 + fr;
                    float v = acc[m][n][j] + b2e[col];
                    atomicAdd(&y[(size_t)tok * DIM + col], g * v);
                }
            }
        }
    }
}

// ---------------- workspace layout ----------------
static constexpr size_t XB_OFF   = 0;
static constexpr size_t W1B_OFF  = XB_OFF  + (size_t)N_TOK * DIM * 2;        // 16 MB
static constexpr size_t W2B_OFF  = W1B_OFF + (size_t)NEXP * HID * DIM * 2;   // +64 MB
static constexpr size_t HG_OFF   = W2B_OFF + (size_t)NEXP * DIM * HID * 2;   // +64 MB
static constexpr size_t RT_OFF   = HG_OFF  + (size_t)M_TOT * HID * 2;        // +128 MB
static constexpr size_t RG_OFF   = RT_OFF  + (size_t)M_TOT * 4;
static constexpr size_t TI_OFF   = RG_OFF  + (size_t)M_TOT * 4;
static constexpr size_t TG_OFF   = TI_OFF  + (size_t)N_TOK * TOPK * 4;
static constexpr size_t META_OFF = TG_OFF  + (size_t)N_TOK * TOPK * 4;
static constexpr size_t WS_NEED  = META_OFF + 256;

extern "C" void kernel_launch(void* const* d_in, const int* in_sizes, int n_in,
                              void* d_out, int out_size, void* d_ws, size_t ws_size,
                              hipStream_t stream)
{
    if (ws_size < WS_NEED) return;  // workspace too small — fail loudly via validation

    const float* x  = (const float*)d_in[0];
    const float* rw = (const float*)d_in[1];
    const float* rb = (const float*)d_in[2];
    const float* w1 = (const float*)d_in[3];
    const float* b1 = (const float*)d_in[4];
    const float* w2 = (const float*)d_in[5];
    const float* b2 = (const float*)d_in[6];
    float* y = (float*)d_out;

    char* ws = (char*)d_ws;
    unsigned short* xb  = (unsigned short*)(ws + XB_OFF);
    unsigned short* w1b = (unsigned short*)(ws + W1B_OFF);
    unsigned short* w2b = (unsigned short*)(ws + W2B_OFF);
    unsigned short* hg  = (unsigned short*)(ws + HG_OFF);
    int*   rowtok  = (int*)  (ws + RT_OFF);
    float* rowgate = (float*)(ws + RG_OFF);
    int*   tidx    = (int*)  (ws + TI_OFF);
    float* tgate   = (float*)(ws + TG_OFF);
    int*   meta    = (int*)  (ws + META_OFF);
    int* counts  = meta;        // 8 ints
    int* counts2 = meta + 8;    // 8 ints
    int* offsets = meta + 16;   // 8 ints

    hipMemsetAsync(meta, 0, 64, stream);
    hipMemsetAsync(y, 0, (size_t)out_size * 4, stream);

    cvt_kernel<<<2048, 256, 0, stream>>>(x,  xb,  N_TOK*DIM/4);
    cvt_kernel<<<2048, 256, 0, stream>>>(w1, w1b, NEXP*HID*DIM/4);
    cvt_kernel<<<2048, 256, 0, stream>>>(w2, w2b, NEXP*DIM*HID/4);

    router_kernel<<<N_TOK, 64, 0, stream>>>(x, rw, rb, tidx, tgate, counts);
    prefix_kernel<<<1, 64, 0, stream>>>(counts, offsets);
    assign_kernel<<<N_TOK/256, 256, 0, stream>>>(tidx, tgate, offsets, counts2, rowtok, rowgate);

    gemm1_kernel<<<dim3(HID/128, 64, NEXP), 256, 0, stream>>>(xb, w1b, b1, rowtok, counts, offsets, hg);
    gemm2_kernel<<<dim3(DIM/128, 64, NEXP), 256, 0, stream>>>(hg, w2b, b2, rowtok, rowgate, counts, offsets, y);
}

// Round 2
// 911.234 us; speedup vs baseline: 1.1256x; 1.1256x over previous
//
#include <hip/hip_runtime.h>
#include <hip/hip_bf16.h>

#define N_TOK 8192
#define DIM   1024
#define HID   4096
#define NEXP  8
#define TOPK  2
#define M_TOT (N_TOK*TOPK)

typedef __bf16 bf16x8 __attribute__((ext_vector_type(8)));
typedef float  f32x4  __attribute__((ext_vector_type(4)));

__device__ __forceinline__ unsigned short f2bf(float f) {
    union { __hip_bfloat16 h; unsigned short u; } c;
    c.h = __float2bfloat16(f);
    return c.u;
}

// async global->LDS, 16B per lane. LDS dest must be wave-uniform base;
// lane's 16B lands at base + lane*16 (linear). Global src is per-lane.
__device__ __forceinline__ void gload16(const unsigned short* g, unsigned short* l) {
    __builtin_amdgcn_global_load_lds(
        (const __attribute__((address_space(1))) void*)g,
        (__attribute__((address_space(3))) void*)l,
        16, 0, 0);
}

// ---------------- fp32 -> bf16 conversion (vectorized) ----------------
__global__ void cvt_kernel(const float* __restrict__ in, unsigned short* __restrict__ out, int n4) {
    int i = blockIdx.x * blockDim.x + threadIdx.x;
    int stride = gridDim.x * blockDim.x;
    for (; i < n4; i += stride) {
        float4 v = reinterpret_cast<const float4*>(in)[i];
        ushort4 o;
        o.x = f2bf(v.x); o.y = f2bf(v.y); o.z = f2bf(v.z); o.w = f2bf(v.w);
        reinterpret_cast<ushort4*>(out)[i] = o;
    }
}

// ---------------- router: logits, softmax, top-2, counts ----------------
__global__ __launch_bounds__(64) void router_kernel(
    const float* __restrict__ x, const float* __restrict__ rw, const float* __restrict__ rb,
    int* __restrict__ tidx, float* __restrict__ tgate, int* __restrict__ counts)
{
    int t = blockIdx.x;
    int lane = threadIdx.x;
    const float* xr = x + (size_t)t * DIM;
    float acc[NEXP];
#pragma unroll
    for (int e = 0; e < NEXP; ++e) acc[e] = 0.f;
    for (int i = lane; i < DIM; i += 64) {
        float xv = xr[i];
#pragma unroll
        for (int e = 0; e < NEXP; ++e) acc[e] += xv * rw[e*DIM + i];
    }
#pragma unroll
    for (int e = 0; e < NEXP; ++e) {
        float v = acc[e];
#pragma unroll
        for (int off = 32; off >= 1; off >>= 1) v += __shfl_xor(v, off);
        acc[e] = v + rb[e];
    }
    int i0 = 0;
#pragma unroll
    for (int e = 1; e < NEXP; ++e) if (acc[e] > acc[i0]) i0 = e;
    int i1 = (i0 == 0) ? 1 : 0;
#pragma unroll
    for (int e = 0; e < NEXP; ++e) if (e != i0 && acc[e] > acc[i1]) i1 = e;

    float mx = acc[i0];
    float den = 0.f;
    float pe[NEXP];
#pragma unroll
    for (int e = 0; e < NEXP; ++e) { pe[e] = __expf(acc[e] - mx); den += pe[e]; }
    float inv = 1.f / den;
    if (lane == 0) {
        tidx[2*t]   = i0;  tidx[2*t+1]  = i1;
        tgate[2*t]  = pe[i0]*inv; tgate[2*t+1] = pe[i1]*inv;
        atomicAdd(&counts[i0], 1);
        atomicAdd(&counts[i1], 1);
    }
}

__global__ void prefix_kernel(const int* __restrict__ counts, int* __restrict__ offsets) {
    if (threadIdx.x == 0 && blockIdx.x == 0) {
        int s = 0;
        for (int e = 0; e < NEXP; ++e) { offsets[e] = s; s += counts[e]; }
    }
}

__global__ void assign_kernel(const int* __restrict__ tidx, const float* __restrict__ tgate,
                              const int* __restrict__ offsets, int* __restrict__ counts2,
                              int* __restrict__ rowtok, float* __restrict__ rowgate)
{
    int t = blockIdx.x * blockDim.x + threadIdx.x;
    if (t >= N_TOK) return;
#pragma unroll
    for (int k = 0; k < TOPK; ++k) {
        int e = tidx[2*t+k];
        int pos = atomicAdd(&counts2[e], 1);
        int r = offsets[e] + pos;
        rowtok[r]  = t;
        rowgate[r] = tgate[2*t+k];
    }
}

// ---------------- GEMM1: h = gelu(Xg @ w1[e]^T + b1[e]), store bf16 ----------------
// 128x128 tile, BK=32, 4 waves x (4x4) 16x16x32 MFMA frags; global_load_lds staging.
__global__ __launch_bounds__(256) void gemm1_kernel(
    const unsigned short* __restrict__ xb,      // N x D bf16
    const unsigned short* __restrict__ w1b,     // E x H x D bf16
    const float* __restrict__ b1,               // E x H
    const int* __restrict__ rowtok,
    const int* __restrict__ counts, const int* __restrict__ offsets,
    unsigned short* __restrict__ hg)            // M_TOT x H bf16 (compact)
{
    int e   = blockIdx.z;
    int cnt = counts[e];
    int mt  = blockIdx.y;
    if (mt * 128 >= cnt) return;
    int base  = offsets[e];
    int nbase = blockIdx.x * 128;

    __shared__ unsigned short As[128*32];   // row-major [128][32], linear for gload16
    __shared__ unsigned short Bs[128*32];
    __shared__ int rowids[128];

    int tid = threadIdx.x;
    if (tid < 128) {
        int r = mt*128 + tid;
        rowids[tid] = rowtok[base + (r < cnt ? r : cnt - 1)];
    }
    __syncthreads();

    int lane = tid & 63;
    int wid  = tid >> 6;
    // staging: chunk c = wid*2+q covers tile rows [16c,16c+16); lane l -> row 16c+(l>>2), 16B slot l&3
    int c0 = wid*2, c1 = wid*2 + 1;
    int sr0 = c0*16 + (lane >> 2);
    int sr1 = c1*16 + (lane >> 2);
    int slot = (lane & 3) << 3;  // element offset (8 bf16 = 16 B)

    const unsigned short* wE  = w1b + (size_t)e * HID * DIM;
    const unsigned short* aG0 = xb + (size_t)rowids[sr0] * DIM + slot;
    const unsigned short* aG1 = xb + (size_t)rowids[sr1] * DIM + slot;
    const unsigned short* bG0 = wE + (size_t)(nbase + sr0) * DIM + slot;
    const unsigned short* bG1 = wE + (size_t)(nbase + sr1) * DIM + slot;
    unsigned short* asD0 = &As[c0*512];   // wave-uniform LDS bases
    unsigned short* asD1 = &As[c1*512];
    unsigned short* bsD0 = &Bs[c0*512];
    unsigned short* bsD1 = &Bs[c1*512];

    int wr = (wid >> 1) << 6;
    int wc = (wid & 1)  << 6;
    int fr = lane & 15;
    int fk = (lane >> 4) << 3;

    f32x4 acc[4][4];
#pragma unroll
    for (int m = 0; m < 4; ++m)
#pragma unroll
        for (int n = 0; n < 4; ++n)
#pragma unroll
            for (int j = 0; j < 4; ++j) acc[m][n][j] = 0.f;

    for (int k0 = 0; k0 < DIM; k0 += 32) {
        gload16(aG0 + k0, asD0);
        gload16(aG1 + k0, asD1);
        gload16(bG0 + k0, bsD0);
        gload16(bG1 + k0, bsD1);
        __syncthreads();   // drains vmcnt -> tile resident

        bf16x8 af[4], bfr[4];
#pragma unroll
        for (int m = 0; m < 4; ++m) af[m]  = *(const bf16x8*)&As[(wr + m*16 + fr)*32 + fk];
#pragma unroll
        for (int n = 0; n < 4; ++n) bfr[n] = *(const bf16x8*)&Bs[(wc + n*16 + fr)*32 + fk];
#pragma unroll
        for (int m = 0; m < 4; ++m)
#pragma unroll
            for (int n = 0; n < 4; ++n)
                acc[m][n] = __builtin_amdgcn_mfma_f32_16x16x32_bf16(af[m], bfr[n], acc[m][n], 0, 0, 0);
        __syncthreads();   // all reads done before next stage overwrites
    }

    const float* b1e = b1 + (size_t)e * HID;
#pragma unroll
    for (int m = 0; m < 4; ++m) {
        int rbase = wr + m*16 + ((lane >> 4) << 2);
#pragma unroll
        for (int j = 0; j < 4; ++j) {
            int grow = mt*128 + rbase + j;
            if (grow < cnt) {
                size_t rowoff = (size_t)(base + grow) * HID;
#pragma unroll
                for (int n = 0; n < 4; ++n) {
                    int col = nbase + wc + n*16 + fr;
                    float v = acc[m][n][j] + b1e[col];
                    // gelu (tanh approximation, jax default)
                    float u  = 0.7978845608028654f * (v + 0.044715f * v * v * v);
                    float ex = __expf(2.f * u);
                    float th = 1.f - 2.f / (ex + 1.f);
                    float g  = 0.5f * v * (1.f + th);
                    hg[rowoff + col] = f2bf(g);
                }
            }
        }
    }
}

// ---------------- GEMM2: y[tok] += gate * (hg @ w2[e]^T + b2[e]) ----------------
__global__ __launch_bounds__(256) void gemm2_kernel(
    const unsigned short* __restrict__ hg,      // M_TOT x H bf16
    const unsigned short* __restrict__ w2b,     // E x D x H bf16
    const float* __restrict__ b2,               // E x D
    const int* __restrict__ rowtok, const float* __restrict__ rowgate,
    const int* __restrict__ counts, const int* __restrict__ offsets,
    float* __restrict__ y)                      // N x D fp32 (pre-zeroed)
{
    int e   = blockIdx.z;
    int cnt = counts[e];
    int mt  = blockIdx.y;
    if (mt * 128 >= cnt) return;
    int base  = offsets[e];
    int nbase = blockIdx.x * 128;

    __shared__ unsigned short As[128*32];
    __shared__ unsigned short Bs[128*32];

    int tid  = threadIdx.x;
    int lane = tid & 63;
    int wid  = tid >> 6;
    int c0 = wid*2, c1 = wid*2 + 1;
    int sr0 = c0*16 + (lane >> 2);
    int sr1 = c1*16 + (lane >> 2);
    int slot = (lane & 3) << 3;

    int ar0 = mt*128 + sr0; if (ar0 >= cnt) ar0 = cnt - 1;
    int ar1 = mt*128 + sr1; if (ar1 >= cnt) ar1 = cnt - 1;
    const unsigned short* wE  = w2b + (size_t)e * DIM * HID;
    const unsigned short* aG0 = hg + (size_t)(base + ar0) * HID + slot;
    const unsigned short* aG1 = hg + (size_t)(base + ar1) * HID + slot;
    const unsigned short* bG0 = wE + (size_t)(nbase + sr0) * HID + slot;
    const unsigned short* bG1 = wE + (size_t)(nbase + sr1) * HID + slot;
    unsigned short* asD0 = &As[c0*512];
    unsigned short* asD1 = &As[c1*512];
    unsigned short* bsD0 = &Bs[c0*512];
    unsigned short* bsD1 = &Bs[c1*512];

    int wr = (wid >> 1) << 6;
    int wc = (wid & 1)  << 6;
    int fr = lane & 15;
    int fk = (lane >> 4) << 3;

    f32x4 acc[4][4];
#pragma unroll
    for (int m = 0; m < 4; ++m)
#pragma unroll
        for (int n = 0; n < 4; ++n)
#pragma unroll
            for (int j = 0; j < 4; ++j) acc[m][n][j] = 0.f;

    for (int k0 = 0; k0 < HID; k0 += 32) {
        gload16(aG0 + k0, asD0);
        gload16(aG1 + k0, asD1);
        gload16(bG0 + k0, bsD0);
        gload16(bG1 + k0, bsD1);
        __syncthreads();

        bf16x8 af[4], bfr[4];
#pragma unroll
        for (int m = 0; m < 4; ++m) af[m]  = *(const bf16x8*)&As[(wr + m*16 + fr)*32 + fk];
#pragma unroll
        for (int n = 0; n < 4; ++n) bfr[n] = *(const bf16x8*)&Bs[(wc + n*16 + fr)*32 + fk];
#pragma unroll
        for (int m = 0; m < 4; ++m)
#pragma unroll
            for (int n = 0; n < 4; ++n)
                acc[m][n] = __builtin_amdgcn_mfma_f32_16x16x32_bf16(af[m], bfr[n], acc[m][n], 0, 0, 0);
        __syncthreads();
    }

    const float* b2e = b2 + (size_t)e * DIM;
#pragma unroll
    for (int m = 0; m < 4; ++m) {
        int rbase = wr + m*16 + ((lane >> 4) << 2);
#pragma unroll
        for (int j = 0; j < 4; ++j) {
            int grow = mt*128 + rbase + j;
            if (grow < cnt) {
                int tok = rowtok[base + grow];
                float g = rowgate[base + grow];
#pragma unroll
                for (int n = 0; n < 4; ++n) {
                    int col = nbase + wc + n*16 + fr;
                    float v = acc[m][n][j] + b2e[col];
                    atomicAdd(&y[(size_t)tok * DIM + col], g * v);
                }
            }
        }
    }
}

// ---------------- workspace layout ----------------
static constexpr size_t XB_OFF   = 0;
static constexpr size_t W1B_OFF  = XB_OFF  + (size_t)N_TOK * DIM * 2;        // 16 MB
static constexpr size_t W2B_OFF  = W1B_OFF + (size_t)NEXP * HID * DIM * 2;   // +64 MB
static constexpr size_t HG_OFF   = W2B_OFF + (size_t)NEXP * DIM * HID * 2;   // +64 MB
static constexpr size_t RT_OFF   = HG_OFF  + (size_t)M_TOT * HID * 2;        // +128 MB
static constexpr size_t RG_OFF   = RT_OFF  + (size_t)M_TOT * 4;
static constexpr size_t TI_OFF   = RG_OFF  + (size_t)M_TOT * 4;
static constexpr size_t TG_OFF   = TI_OFF  + (size_t)N_TOK * TOPK * 4;
static constexpr size_t META_OFF = TG_OFF  + (size_t)N_TOK * TOPK * 4;
static constexpr size_t WS_NEED  = META_OFF + 256;

extern "C" void kernel_launch(void* const* d_in, const int* in_sizes, int n_in,
                              void* d_out, int out_size, void* d_ws, size_t ws_size,
                              hipStream_t stream)
{
    if (ws_size < WS_NEED) return;

    const float* x  = (const float*)d_in[0];
    const float* rw = (const float*)d_in[1];
    const float* rb = (const float*)d_in[2];
    const float* w1 = (const float*)d_in[3];
    const float* b1 = (const float*)d_in[4];
    const float* w2 = (const float*)d_in[5];
    const float* b2 = (const float*)d_in[6];
    float* y = (float*)d_out;

    char* ws = (char*)d_ws;
    unsigned short* xb  = (unsigned short*)(ws + XB_OFF);
    unsigned short* w1b = (unsigned short*)(ws + W1B_OFF);
    unsigned short* w2b = (unsigned short*)(ws + W2B_OFF);
    unsigned short* hg  = (unsigned short*)(ws + HG_OFF);
    int*   rowtok  = (int*)  (ws + RT_OFF);
    float* rowgate = (float*)(ws + RG_OFF);
    int*   tidx    = (int*)  (ws + TI_OFF);
    float* tgate   = (float*)(ws + TG_OFF);
    int*   meta    = (int*)  (ws + META_OFF);
    int* counts  = meta;        // 8 ints
    int* counts2 = meta + 8;    // 8 ints
    int* offsets = meta + 16;   // 8 ints

    hipMemsetAsync(meta, 0, 64, stream);
    hipMemsetAsync(y, 0, (size_t)out_size * 4, stream);

    cvt_kernel<<<2048, 256, 0, stream>>>(x,  xb,  N_TOK*DIM/4);
    cvt_kernel<<<2048, 256, 0, stream>>>(w1, w1b, NEXP*HID*DIM/4);
    cvt_kernel<<<2048, 256, 0, stream>>>(w2, w2b, NEXP*DIM*HID/4);

    router_kernel<<<N_TOK, 64, 0, stream>>>(x, rw, rb, tidx, tgate, counts);
    prefix_kernel<<<1, 64, 0, stream>>>(counts, offsets);
    assign_kernel<<<N_TOK/256, 256, 0, stream>>>(tidx, tgate, offsets, counts2, rowtok, rowgate);

    gemm1_kernel<<<dim3(HID/128, 64, NEXP), 256, 0, stream>>>(xb, w1b, b1, rowtok, counts, offsets, hg);
    gemm2_kernel<<<dim3(DIM/128, 64, NEXP), 256, 0, stream>>>(hg, w2b, b2, rowtok, rowgate, counts, offsets, y);
}